// Round 20
// baseline (84.657 us; speedup 1.0000x reference)
//
#include <hip/hip_runtime.h>
#include <stdint.h>

typedef unsigned short u16;
typedef __attribute__((ext_vector_type(8))) short short8;
typedef __attribute__((ext_vector_type(8))) u16 ushort8;
typedef __attribute__((ext_vector_type(4))) float f32x4;
typedef __attribute__((ext_vector_type(16))) float f32x16;
typedef __attribute__((ext_vector_type(4))) unsigned int uint4v;

#define LOG2E 1.44269504088896f

__device__ __forceinline__ u16 f2bf(float f) {
  unsigned int u = __builtin_bit_cast(unsigned int, f);
  u += 0x7FFF + ((u >> 16) & 1);  // RNE; inputs finite
  return (u16)(u >> 16);
}
// HW packed f32->bf16 (RNE): lo = a, hi = b.
__device__ __forceinline__ unsigned int cvtpk(float a, float b) {
  unsigned int r;
  asm("v_cvt_pk_bf16_f32 %0, %1, %2" : "=v"(r) : "v"(a), "v"(b));
  return r;
}
// v_permlane32_swap_b32: a.hi32lanes <-> b.lo32lanes.
__device__ __forceinline__ void plswap(unsigned int& a, unsigned int& b) {
  asm("v_permlane32_swap_b32 %0, %1" : "+v"(a), "+v"(b));
}
__device__ __forceinline__ void gload_lds16(const u16* g, u16* l) {
  __builtin_amdgcn_global_load_lds((const __attribute__((address_space(1))) void*)g,
                                   (__attribute__((address_space(3))) void*)l, 16, 0, 0);
}

// ---------------- fused fp32 -> bf16 convert (all 5 tensors, 1 launch) ----------
__global__ __launch_bounds__(256) void cvt_all(
    const float* __restrict__ s0, u16* __restrict__ d0, int n0,
    const float* __restrict__ s1, u16* __restrict__ d1, int n1,
    const float* __restrict__ s2, u16* __restrict__ d2, int n2,
    const float* __restrict__ s3, u16* __restrict__ d3, int n3,
    const float* __restrict__ s4, u16* __restrict__ d4, int n4) {
  const int tid0 = blockIdx.x * 256 + threadIdx.x;
  const int stride = gridDim.x * 256 * 4;
#define CVT_SEG(S, D, N)                                       \
  for (int i = tid0 * 4; i < (N); i += stride) {               \
    float4 v = *(const float4*)((S) + i);                      \
    *(uint2*)((D) + i) = make_uint2(cvtpk(v.x, v.y), cvtpk(v.z, v.w)); \
  }
  CVT_SEG(s0, d0, n0)
  CVT_SEG(s1, d1, n1)
  CVT_SEG(s2, d2, n2)
  CVT_SEG(s3, d3, n3)
  CVT_SEG(s4, d4, n4)
#undef CVT_SEG
}

// ---------------- 128x128 bf16 GEMM, C = A * B^T (+bias): qkv ----------
// 2-phase double-buffer + T4 counted vmcnt; LDS XOR-swizzled (T2);
// XCD block swizzle (T1). Epilogue -> FRAGMENT-MAJOR packed q/k/v
// (q pre-scaled by 0.125*log2e so attention uses exp2).
#define CTS 130  // ct row stride (u16): bank step 65 == 1 mod 32
__global__ __launch_bounds__(256) void gemm128q(
    const u16* __restrict__ A, const u16* __restrict__ B,
    const float* __restrict__ bias,
    u16* __restrict__ qo, u16* __restrict__ ko, u16* __restrict__ vto,
    int M, int N, int K) {
  __shared__ u16 smem[4 * 128 * 64];  // [2 dbuf][A,B] 64 KB; epilogue reuses as ct
  const int tid = threadIdx.x;
  const int lane = tid & 63, wave = tid >> 6;
  const int wr = wave >> 1, wc = wave & 1;
  const int l15 = lane & 15, l4 = lane >> 4;
  const int fid = blockIdx.y * gridDim.x + blockIdx.x;
  const int cpx = (gridDim.x * gridDim.y) >> 3;  // nwg % 8 == 0
  const int swz = (fid & 7) * cpx + (fid >> 3);
  const int bxs = swz % gridDim.x, bys = swz / gridDim.x;
  const int bm = bys << 7, bn = bxs << 7;
  f32x4 acc[4][4] = {};
  const int nkt = K >> 6;

#define STAGE(buf, kt)                                                        \
  {                                                                           \
    u16* As_ = smem + (buf) * 16384;                                          \
    u16* Bs_ = As_ + 8192;                                                    \
    const int k0_ = (kt) << 6;                                                \
    _Pragma("unroll") for (int j = 0; j < 4; ++j) {                           \
      const int cbase = j * 256 + wave * 64;                                  \
      const int chunk = cbase + lane;                                         \
      const int row = chunk >> 3;                                             \
      const int co = (((chunk & 7) ^ (row & 7)) << 3);                        \
      gload_lds16(A + (size_t)(bm + row) * K + k0_ + co, As_ + cbase * 8);    \
      gload_lds16(B + (size_t)(bn + row) * K + k0_ + co, Bs_ + cbase * 8);    \
    }                                                                         \
  }

  STAGE(0, 0)
  int cur = 0;
  for (int kt = 0; kt < nkt; ++kt) {
    if (kt + 1 < nkt) {
      STAGE(cur ^ 1, kt + 1)  // prefetch next tile: stays in flight past B1
      asm volatile("s_waitcnt vmcnt(8)" ::: "memory");  // prev tile's 8 retired
    } else {
      asm volatile("s_waitcnt vmcnt(0)" ::: "memory");  // final tile: drain
    }
    __builtin_amdgcn_s_barrier();  // B1: everyone's cur tile is in LDS
    const u16* As = smem + cur * 16384;
    const u16* Bs = As + 8192;
    short8 af[2][4], bf[2][4];
#pragma unroll
    for (int kc = 0; kc < 2; ++kc)
#pragma unroll
      for (int i = 0; i < 4; ++i) {
        const int rA = wr * 64 + i * 16 + l15;
        const int rB = wc * 64 + i * 16 + l15;
        af[kc][i] = *(const short8*)((const char*)As +
            (((rA * 64 + kc * 32 + l4 * 8) * 2) ^ ((rA & 7) << 4)));
        bf[kc][i] = *(const short8*)((const char*)Bs +
            (((rB * 64 + kc * 32 + l4 * 8) * 2) ^ ((rB & 7) << 4)));
      }
#pragma unroll
    for (int kc = 0; kc < 2; ++kc)
#pragma unroll
      for (int mi = 0; mi < 4; ++mi)
#pragma unroll
        for (int ni = 0; ni < 4; ++ni)
          acc[mi][ni] = __builtin_amdgcn_mfma_f32_16x16x32_bf16(
              af[kc][mi], bf[kc][ni], acc[mi][ni], 0, 0, 0);
    __builtin_amdgcn_s_barrier();  // B2: all reads of cur done -> overwrite ok
    cur ^= 1;
  }
#undef STAGE

  // stage C tile to LDS as bf16, then scatter to packed layouts
  u16* ct = smem;  // [128][CTS]  (loop ended at B2; no vmem outstanding)
  const int which = bn / 768;  // 0:q 1:k 2:v (768 = 6*128, boundaries align)
  const float sc = (which == 0) ? 0.125f * LOG2E : 1.0f;  // SDPA scale + log2e fold
#pragma unroll
  for (int ni = 0; ni < 4; ++ni) {
    const int col = wc * 64 + ni * 16 + l15;
    const float bv = bias[bn + col];
#pragma unroll
    for (int mi = 0; mi < 4; ++mi)
#pragma unroll
      for (int j = 0; j < 4; ++j) {
        const int row = wr * 64 + mi * 16 + l4 * 4 + j;
        ct[row * CTS + col] = f2bf((acc[mi][ni][j] + bv) * sc);
      }
  }
  __syncthreads();
  const int nrel = bn - which * 768;
  const int head0 = nrel >> 6;  // 128-wide tile covers exactly 2 heads
  const int b = bm >> 10;       // 128-row tile stays inside one batch
  if (which < 2) {
    u16* dst0 = which ? ko : qo;
    const int row = tid >> 1, hp = tid & 1;  // hp selects head parity
    const int head = head0 + hp;
    const int pos = (bm + row) & 1023;
    const u16* s = ct + row * CTS + hp * 64;
    u16* base = dst0 + ((size_t)(b * 12 + head)) * 65536;
    if (which == 0) {
      const int qsub = pos >> 5, lq = pos & 31;
#pragma unroll
      for (int g = 0; g < 8; ++g) {
        const int c = g >> 1, hi = g & 1;
        *(ushort8*)(base + ((qsub * 4 + c) * 64 + hi * 32 + lq) * 8) =
            *(const ushort8*)(s + g * 8);
      }
    } else {
      const int t = pos >> 6, hf = (pos >> 5) & 1, lq = pos & 31;
#pragma unroll
      for (int g = 0; g < 8; ++g) {
        const int c = g >> 1, hi = g & 1;
        *(ushort8*)(base + (((t * 4 + c) * 2 + hf) * 64 + hi * 32 + lq) * 8) =
            *(const ushort8*)(s + g * 8);
      }
    }
  } else {
    const int c = tid >> 1, seg = tid & 1;
    const int head = head0 + (c >> 6), dd = c & 63;
    const int posbase = (bm & 1023) + seg * 64;
    const int t = posbase >> 6;
    const int half = dd >> 5, lqd = dd & 31;
    u16* base = vto + ((size_t)(b * 12 + head)) * 65536;
    const u16* s = ct + (seg * 64) * CTS + c;
#pragma unroll
    for (int g = 0; g < 8; ++g) {
      ushort8 o;
#pragma unroll
      for (int e = 0; e < 8; ++e) o[e] = s[(g * 8 + e) * CTS];
      *(ushort8*)(base + (((t * 4 + (g >> 1)) * 2 + half) * 64 + (g & 1) * 32 + lqd) * 8) = o;
    }
  }
}

// ---------------- 64x64 bf16 GEMM for proj (T4 counted vmcnt too) ------------
__global__ __launch_bounds__(256) void gemm64(
    const u16* __restrict__ A, const u16* __restrict__ B,
    const float* __restrict__ bias, float* __restrict__ fout,
    int M, int N, int K) {
  __shared__ u16 smem[2 * 8192];  // [2 dbuf][A 4096 + B 4096 u16] = 32 KB
  const int tid = threadIdx.x;
  const int lane = tid & 63, wave = tid >> 6;
  const int wr = wave >> 1, wc = wave & 1;
  const int l15 = lane & 15, l4 = lane >> 4;
  const int fid = blockIdx.y * gridDim.x + blockIdx.x;
  const int cpx = (gridDim.x * gridDim.y) >> 3;  // 768 % 8 == 0
  const int swz = (fid & 7) * cpx + (fid >> 3);
  const int bxs = swz % gridDim.x, bys = swz / gridDim.x;
  const int bm = bys << 6, bn = bxs << 6;
  f32x4 acc[2][2] = {};
  const int nkt = K >> 6;

#define STAGE64(buf, kt)                                                      \
  {                                                                           \
    u16* As_ = smem + (buf) * 8192;                                           \
    u16* Bs_ = As_ + 4096;                                                    \
    const int k0_ = (kt) << 6;                                                \
    _Pragma("unroll") for (int j = 0; j < 2; ++j) {                           \
      const int cbase = j * 256 + wave * 64;                                  \
      const int chunk = cbase + lane;                                         \
      const int row = chunk >> 3;                                             \
      const int co = (((chunk & 7) ^ (row & 7)) << 3);                        \
      gload_lds16(A + (size_t)(bm + row) * K + k0_ + co, As_ + cbase * 8);    \
      gload_lds16(B + (size_t)(bn + row) * K + k0_ + co, Bs_ + cbase * 8);    \
    }                                                                         \
  }

  STAGE64(0, 0)
  int cur = 0;
  for (int kt = 0; kt < nkt; ++kt) {
    if (kt + 1 < nkt) {
      STAGE64(cur ^ 1, kt + 1)
      asm volatile("s_waitcnt vmcnt(4)" ::: "memory");
    } else {
      asm volatile("s_waitcnt vmcnt(0)" ::: "memory");
    }
    __builtin_amdgcn_s_barrier();  // B1
    const u16* As = smem + cur * 8192;
    const u16* Bs = As + 4096;
    short8 af[2][2], bf[2][2];
#pragma unroll
    for (int kc = 0; kc < 2; ++kc)
#pragma unroll
      for (int i = 0; i < 2; ++i) {
        const int rA = wr * 32 + i * 16 + l15;
        const int rB = wc * 32 + i * 16 + l15;
        af[kc][i] = *(const short8*)((const char*)As +
            (((rA * 64 + kc * 32 + l4 * 8) * 2) ^ ((rA & 7) << 4)));
        bf[kc][i] = *(const short8*)((const char*)Bs +
            (((rB * 64 + kc * 32 + l4 * 8) * 2) ^ ((rB & 7) << 4)));
      }
#pragma unroll
    for (int kc = 0; kc < 2; ++kc)
#pragma unroll
      for (int mi = 0; mi < 2; ++mi)
#pragma unroll
        for (int ni = 0; ni < 2; ++ni)
          acc[mi][ni] = __builtin_amdgcn_mfma_f32_16x16x32_bf16(
              af[kc][mi], bf[kc][ni], acc[mi][ni], 0, 0, 0);
    __builtin_amdgcn_s_barrier();  // B2
    cur ^= 1;
  }
#undef STAGE64

#pragma unroll
  for (int ni = 0; ni < 2; ++ni) {
    const int col = wc * 32 + ni * 16 + l15;
    const float bv = bias[bn + col];
#pragma unroll
    for (int mi = 0; mi < 2; ++mi)
#pragma unroll
      for (int j = 0; j < 4; ++j) {
        const int row = wr * 32 + mi * 16 + l4 * 4 + j;
        fout[(size_t)(bm + row) * N + bn + col] = acc[mi][ni][j] + bv;
      }
  }
}

// ---------------- fused attention; rel fused; K AND V register-prefetch -------
// grid (48 bh, 16 qtiles64), 256 threads = 4 waves = (2 q-subtiles x 2 key-halves).
// NEW (R20): V is prefetched one full tile ahead, symmetric with K. R12 proved
// the relevant miss latency (~600-900cy L3/far-L2) needs a full-tile lead; V's
// old same-iteration issue gave only ~400cy cover -> ~500cy stall at every PV.
// vb[2][8] parity-indexed in a fully unrolled loop (static idx, rule #20 safe);
// in-order vmcnt: PV(t)'s wait on V(t) leaves the 16 newer prefetches in flight.
__global__ __launch_bounds__(256) void attn_kernel(
    const u16* __restrict__ pq, const u16* __restrict__ pk,
    const u16* __restrict__ pv, const u16* __restrict__ th,
    const u16* __restrict__ tw, u16* __restrict__ aout) {
  const int bh = blockIdx.x, qt = blockIdx.y;
  const int tid = threadIdx.x, lane = tid & 63, wave = tid >> 6;
  const int wq = wave >> 1, wk = wave & 1;
  const int lq = lane & 31, hi = lane >> 5;
  const int q0 = qt * 64 + wq * 32;
  const u16* Qb = pq + (size_t)bh * 65536;
  const u16* Kb = pk + (size_t)bh * 65536;
  const u16* Vb = pv + (size_t)bh * 65536;
  __shared__ float lsums[2][2][32];
  __shared__ char shraw[24576];          // pd[2][64][32] + rh[2][32][32], then part
  float* pd = (float*)shraw;             // [wq][j][q]
  float* rhl = (float*)(shraw + 16384);  // [wq][kh][q]
  float* part = (float*)shraw;           // [wq][wk][lane][17] (aliases; see barriers)
  const int qsub = qt * 2 + wq;          // spatial h of this wave's q-rows
  short8 qf[4];
#pragma unroll
  for (int c = 0; c < 4; ++c)
    qf[c] = *(const short8*)(Qb + ((qsub * 4 + c) * 64 + lane) * 8);
  // issue first K AND V tiles early; rel computation below covers their latency
  short8 kf[2][8], vb[2][8];
  {
    const int t0 = wk * 8;
#pragma unroll
    for (int c = 0; c < 4; ++c) {
      kf[0][c]     = *(const short8*)(Kb + (((t0 * 4 + c) * 2 + 0) * 64 + lane) * 8);
      kf[0][4 + c] = *(const short8*)(Kb + (((t0 * 4 + c) * 2 + 1) * 64 + lane) * 8);
      vb[0][c]     = *(const short8*)(Vb + (((t0 * 4 + c) * 2 + 0) * 64 + lane) * 8);
      vb[0][4 + c] = *(const short8*)(Vb + (((t0 * 4 + c) * 2 + 1) * 64 + lane) * 8);
    }
  }
  if (wk == 0) {
    // ---- rel_w: pd[j][q] = 8*dot(Tw[j], q) ----
    f32x16 pa{}, pb{};
    const int trB = (lq == 31) ? 62 : 32 + lq;  // clamp; pd[63] never consumed
#pragma unroll
    for (int c = 0; c < 4; ++c) {
      short8 ta = *(const short8*)(tw + (lq * 64 + c * 16 + hi * 8));
      short8 tb = *(const short8*)(tw + (trB * 64 + c * 16 + hi * 8));
      pa = __builtin_amdgcn_mfma_f32_32x32x16_bf16(ta, qf[c], pa, 0, 0, 0);
      pb = __builtin_amdgcn_mfma_f32_32x32x16_bf16(tb, qf[c], pb, 0, 0, 0);
    }
#pragma unroll
    for (int r = 0; r < 16; ++r) {
      const int j = (r & 3) + 8 * (r >> 2) + 4 * hi;
      pd[(wq * 64 + j) * 32 + lq] = pa[r] * 8.0f;
      pd[(wq * 64 + 32 + j) * 32 + lq] = pb[r] * 8.0f;
    }
  } else {
    // ---- rel_h (swapped orientation): rh[kh][q] = 8*dot(Th[qsub-kh+31], q) ----
    f32x16 rha{};
    const int trh = qsub - lq + 31;  // in [qsub, qsub+31] subset of [0,62]
#pragma unroll
    for (int c = 0; c < 4; ++c) {
      short8 ta = *(const short8*)(th + (trh * 64 + c * 16 + hi * 8));
      rha = __builtin_amdgcn_mfma_f32_32x32x16_bf16(ta, qf[c], rha, 0, 0, 0);
    }
#pragma unroll
    for (int r = 0; r < 16; ++r) {
      const int kh = (r & 3) + 8 * (r >> 2) + 4 * hi;
      rhl[(wq * 32 + kh) * 32 + lq] = rha[r] * 8.0f;
    }
  }
  __syncthreads();  // pd + rhl ready
  float rhv[16];
#pragma unroll
  for (int i = 0; i < 16; ++i)
    rhv[i] = rhl[(wq * 32 + 16 * wk + i) * 32 + lq];
  float rw[16];
#pragma unroll
  for (int r = 0; r < 16; ++r)
    rw[r] = pd[(wq * 64 + lq + 31 - ((r & 3) + 8 * (r >> 2) + 4 * hi)) * 32 + lq];
  __syncthreads();  // all pd/rhl reads done -> 'part' may alias the region
  f32x16 o0{}, o1{};
  float lsum = 0.f;
#pragma unroll
  for (int t = 0; t < 8; ++t) {
    const int tt = wk * 8 + t;
    const int cur = t & 1, nxt = cur ^ 1;
    // prefetch next tile's V then K (consumed one full iteration later;
    // nothing this iteration waits on them -> they ride across PV's V-wait)
    if (t < 7) {
      const int tn = tt + 1;
#pragma unroll
      for (int c = 0; c < 4; ++c) {
        vb[nxt][c]     = *(const short8*)(Vb + (((tn * 4 + c) * 2 + 0) * 64 + lane) * 8);
        vb[nxt][4 + c] = *(const short8*)(Vb + (((tn * 4 + c) * 2 + 1) * 64 + lane) * 8);
      }
#pragma unroll
      for (int c = 0; c < 4; ++c) {
        kf[nxt][c]     = *(const short8*)(Kb + (((tn * 4 + c) * 2 + 0) * 64 + lane) * 8);
        kf[nxt][4 + c] = *(const short8*)(Kb + (((tn * 4 + c) * 2 + 1) * 64 + lane) * 8);
      }
    }
    // QK^T from zero C-init: K is in registers (prefetched) -> no wait
    f32x16 s0{}, s1{};
    __builtin_amdgcn_s_setprio(1);
#pragma unroll
    for (int c = 0; c < 4; ++c) {
      s0 = __builtin_amdgcn_mfma_f32_32x32x16_bf16(kf[cur][c], qf[c], s0, 0, 0, 0);
      s1 = __builtin_amdgcn_mfma_f32_32x32x16_bf16(kf[cur][4 + c], qf[c], s1, 0, 0, 0);
    }
    __builtin_amdgcn_s_setprio(0);
    // bias from REGISTERS (rhv static-indexed: t is fully unrolled)
    const float rh0 = rhv[2 * t], rh1 = rhv[2 * t + 1];
    // |S'| <= ~4.5 -> exp2 without max-subtract (log2e folded upstream)
#pragma unroll
    for (int r = 0; r < 16; ++r) {
      s0[r] = exp2f(s0[r] + (rh0 + rw[r]));
      s1[r] = exp2f(s1[r] + (rh1 + rw[r]));
    }
#pragma unroll
    for (int r = 0; r < 16; ++r) lsum += s0[r] + s1[r];
    // HW pack to bf16 + permlane half-exchange -> PV A-fragments (T12)
    unsigned int pw[16];
#pragma unroll
    for (int j = 0; j < 8; ++j) pw[j] = cvtpk(s0[2 * j], s0[2 * j + 1]);
#pragma unroll
    for (int j = 0; j < 8; ++j) pw[8 + j] = cvtpk(s1[2 * j], s1[2 * j + 1]);
    plswap(pw[0], pw[2]);  plswap(pw[1], pw[3]);
    plswap(pw[4], pw[6]);  plswap(pw[5], pw[7]);
    plswap(pw[8], pw[10]); plswap(pw[9], pw[11]);
    plswap(pw[12], pw[14]); plswap(pw[13], pw[15]);
    __builtin_amdgcn_s_setprio(1);
#pragma unroll
    for (int cc = 0; cc < 4; ++cc) {
      uint4v w4 = {pw[cc * 4 + 0], pw[cc * 4 + 1], pw[cc * 4 + 2], pw[cc * 4 + 3]};
      short8 pa = __builtin_bit_cast(short8, w4);
      o0 = __builtin_amdgcn_mfma_f32_32x32x16_bf16(pa, vb[cur][cc], o0, 0, 0, 0);
      o1 = __builtin_amdgcn_mfma_f32_32x32x16_bf16(pa, vb[cur][4 + cc], o1, 0, 0, 0);
    }
    __builtin_amdgcn_s_setprio(0);
  }
  lsum += __shfl_xor(lsum, 32, 64);
  if (hi == 0) lsums[wq][wk][lq] = lsum;
  // store the O-half this wave will NOT finalize (wk==0 finalizes d<32 -> stores o1)
#pragma unroll
  for (int r = 0; r < 16; ++r)
    part[((wq * 2 + wk) * 64 + lane) * 17 + r] = wk ? o0[r] : o1[r];
  __syncthreads();
  const int b = bh / 12, head = bh - b * 12;
  u16* outp = aout + (size_t)b * 1024 * 768 + head * 64 + wk * 32;
#pragma unroll
  for (int r = 0; r < 16; ++r) {
    const int qr = (r & 3) + 8 * (r >> 2) + 4 * hi;
    const float inv = 1.0f / (lsums[wq][0][qr] + lsums[wq][1][qr]);
    const float own = wk ? o1[r] : o0[r];
    const float val = own + part[((wq * 2 + (wk ^ 1)) * 64 + lane) * 17 + r];
    outp[(size_t)(q0 + qr) * 768 + lq] = f2bf(val * inv);
  }
}

// ---------------- launch ----------------
extern "C" void kernel_launch(void* const* d_in, const int* in_sizes, int n_in,
                              void* d_out, int out_size, void* d_ws, size_t ws_size,
                              hipStream_t stream) {
  const float* x = (const float*)d_in[0];
  const float* qkv_w = (const float*)d_in[1];
  const float* qkv_b = (const float*)d_in[2];
  const float* proj_w = (const float*)d_in[3];
  const float* proj_b = (const float*)d_in[4];
  const float* rph = (const float*)d_in[5];
  const float* rpw = (const float*)d_in[6];
  float* out = (float*)d_out;
  char* ws = (char*)d_ws;
  u16* xb     = (u16*)(ws + 0);
  u16* wqkv   = (u16*)(ws + 6291456);
  u16* wproj  = (u16*)(ws + 9830400);
  u16* pq     = (u16*)(ws + 11010048);
  u16* pk     = (u16*)(ws + 17301504);
  u16* pv     = (u16*)(ws + 23592960);
  u16* aout   = (u16*)(ws + 42467328);
  u16* rphb   = (u16*)(ws + 48758784);
  u16* rpwb   = (u16*)(ws + 48766848);

  cvt_all<<<1024, 256, 0, stream>>>(x, xb, 3145728, qkv_w, wqkv, 1769472,
                                    proj_w, wproj, 589824, rph, rphb, 4032,
                                    rpw, rpwb, 4032);
  gemm128q<<<dim3(18, 32), 256, 0, stream>>>(xb, wqkv, qkv_b, pq, pk, pv,
                                             4096, 2304, 768);
  attn_kernel<<<dim3(48, 16), 256, 0, stream>>>(pq, pk, pv, rphb, rpwb, aout);
  gemm64<<<dim3(12, 64), 256, 0, stream>>>(aout, wproj, proj_b, out,
                                           4096, 768, 768);
}

// Round 21
// 77.736 us; speedup vs baseline: 1.0890x; 1.0890x over previous
//
#include <hip/hip_runtime.h>
#include <stdint.h>

typedef unsigned short u16;
typedef __attribute__((ext_vector_type(8))) short short8;
typedef __attribute__((ext_vector_type(8))) u16 ushort8;
typedef __attribute__((ext_vector_type(4))) float f32x4;
typedef __attribute__((ext_vector_type(16))) float f32x16;
typedef __attribute__((ext_vector_type(4))) unsigned int uint4v;

#define LOG2E 1.44269504088896f

__device__ __forceinline__ u16 f2bf(float f) {
  unsigned int u = __builtin_bit_cast(unsigned int, f);
  u += 0x7FFF + ((u >> 16) & 1);  // RNE; inputs finite
  return (u16)(u >> 16);
}
// HW packed f32->bf16 (RNE): lo = a, hi = b.
__device__ __forceinline__ unsigned int cvtpk(float a, float b) {
  unsigned int r;
  asm("v_cvt_pk_bf16_f32 %0, %1, %2" : "=v"(r) : "v"(a), "v"(b));
  return r;
}
// v_permlane32_swap_b32: a.hi32lanes <-> b.lo32lanes.
__device__ __forceinline__ void plswap(unsigned int& a, unsigned int& b) {
  asm("v_permlane32_swap_b32 %0, %1" : "+v"(a), "+v"(b));
}
__device__ __forceinline__ void gload_lds16(const u16* g, u16* l) {
  __builtin_amdgcn_global_load_lds((const __attribute__((address_space(1))) void*)g,
                                   (__attribute__((address_space(3))) void*)l, 16, 0, 0);
}

// ---------------- fused fp32 -> bf16 convert (all 5 tensors, 1 launch) ----------
__global__ __launch_bounds__(256) void cvt_all(
    const float* __restrict__ s0, u16* __restrict__ d0, int n0,
    const float* __restrict__ s1, u16* __restrict__ d1, int n1,
    const float* __restrict__ s2, u16* __restrict__ d2, int n2,
    const float* __restrict__ s3, u16* __restrict__ d3, int n3,
    const float* __restrict__ s4, u16* __restrict__ d4, int n4) {
  const int tid0 = blockIdx.x * 256 + threadIdx.x;
  const int stride = gridDim.x * 256 * 4;
#define CVT_SEG(S, D, N)                                       \
  for (int i = tid0 * 4; i < (N); i += stride) {               \
    float4 v = *(const float4*)((S) + i);                      \
    *(uint2*)((D) + i) = make_uint2(cvtpk(v.x, v.y), cvtpk(v.z, v.w)); \
  }
  CVT_SEG(s0, d0, n0)
  CVT_SEG(s1, d1, n1)
  CVT_SEG(s2, d2, n2)
  CVT_SEG(s3, d3, n3)
  CVT_SEG(s4, d4, n4)
#undef CVT_SEG
}

// ---------------- 128x128 bf16 GEMM, C = A * B^T (+bias): qkv ----------
// 2-phase double-buffer + T4 counted vmcnt; LDS XOR-swizzled (T2);
// XCD block swizzle (T1). Epilogue -> FRAGMENT-MAJOR packed q/k/v
// (q pre-scaled by 0.125*log2e so attention uses exp2).
#define CTS 130  // ct row stride (u16): bank step 65 == 1 mod 32
__global__ __launch_bounds__(256) void gemm128q(
    const u16* __restrict__ A, const u16* __restrict__ B,
    const float* __restrict__ bias,
    u16* __restrict__ qo, u16* __restrict__ ko, u16* __restrict__ vto,
    int M, int N, int K) {
  __shared__ u16 smem[4 * 128 * 64];  // [2 dbuf][A,B] 64 KB; epilogue reuses as ct
  const int tid = threadIdx.x;
  const int lane = tid & 63, wave = tid >> 6;
  const int wr = wave >> 1, wc = wave & 1;
  const int l15 = lane & 15, l4 = lane >> 4;
  const int fid = blockIdx.y * gridDim.x + blockIdx.x;
  const int cpx = (gridDim.x * gridDim.y) >> 3;  // nwg % 8 == 0
  const int swz = (fid & 7) * cpx + (fid >> 3);
  const int bxs = swz % gridDim.x, bys = swz / gridDim.x;
  const int bm = bys << 7, bn = bxs << 7;
  f32x4 acc[4][4] = {};
  const int nkt = K >> 6;

#define STAGE(buf, kt)                                                        \
  {                                                                           \
    u16* As_ = smem + (buf) * 16384;                                          \
    u16* Bs_ = As_ + 8192;                                                    \
    const int k0_ = (kt) << 6;                                                \
    _Pragma("unroll") for (int j = 0; j < 4; ++j) {                           \
      const int cbase = j * 256 + wave * 64;                                  \
      const int chunk = cbase + lane;                                         \
      const int row = chunk >> 3;                                             \
      const int co = (((chunk & 7) ^ (row & 7)) << 3);                        \
      gload_lds16(A + (size_t)(bm + row) * K + k0_ + co, As_ + cbase * 8);    \
      gload_lds16(B + (size_t)(bn + row) * K + k0_ + co, Bs_ + cbase * 8);    \
    }                                                                         \
  }

  STAGE(0, 0)
  int cur = 0;
  for (int kt = 0; kt < nkt; ++kt) {
    if (kt + 1 < nkt) {
      STAGE(cur ^ 1, kt + 1)  // prefetch next tile: stays in flight past B1
      asm volatile("s_waitcnt vmcnt(8)" ::: "memory");  // prev tile's 8 retired
    } else {
      asm volatile("s_waitcnt vmcnt(0)" ::: "memory");  // final tile: drain
    }
    __builtin_amdgcn_s_barrier();  // B1: everyone's cur tile is in LDS
    const u16* As = smem + cur * 16384;
    const u16* Bs = As + 8192;
    short8 af[2][4], bf[2][4];
#pragma unroll
    for (int kc = 0; kc < 2; ++kc)
#pragma unroll
      for (int i = 0; i < 4; ++i) {
        const int rA = wr * 64 + i * 16 + l15;
        const int rB = wc * 64 + i * 16 + l15;
        af[kc][i] = *(const short8*)((const char*)As +
            (((rA * 64 + kc * 32 + l4 * 8) * 2) ^ ((rA & 7) << 4)));
        bf[kc][i] = *(const short8*)((const char*)Bs +
            (((rB * 64 + kc * 32 + l4 * 8) * 2) ^ ((rB & 7) << 4)));
      }
#pragma unroll
    for (int kc = 0; kc < 2; ++kc)
#pragma unroll
      for (int mi = 0; mi < 4; ++mi)
#pragma unroll
        for (int ni = 0; ni < 4; ++ni)
          acc[mi][ni] = __builtin_amdgcn_mfma_f32_16x16x32_bf16(
              af[kc][mi], bf[kc][ni], acc[mi][ni], 0, 0, 0);
    __builtin_amdgcn_s_barrier();  // B2: all reads of cur done -> overwrite ok
    cur ^= 1;
  }
#undef STAGE

  // stage C tile to LDS as bf16, then scatter to packed layouts
  u16* ct = smem;  // [128][CTS]  (loop ended at B2; no vmem outstanding)
  const int which = bn / 768;  // 0:q 1:k 2:v (768 = 6*128, boundaries align)
  const float sc = (which == 0) ? 0.125f * LOG2E : 1.0f;  // SDPA scale + log2e fold
#pragma unroll
  for (int ni = 0; ni < 4; ++ni) {
    const int col = wc * 64 + ni * 16 + l15;
    const float bv = bias[bn + col];
#pragma unroll
    for (int mi = 0; mi < 4; ++mi)
#pragma unroll
      for (int j = 0; j < 4; ++j) {
        const int row = wr * 64 + mi * 16 + l4 * 4 + j;
        ct[row * CTS + col] = f2bf((acc[mi][ni][j] + bv) * sc);
      }
  }
  __syncthreads();
  const int nrel = bn - which * 768;
  const int head0 = nrel >> 6;  // 128-wide tile covers exactly 2 heads
  const int b = bm >> 10;       // 128-row tile stays inside one batch
  if (which < 2) {
    u16* dst0 = which ? ko : qo;
    const int row = tid >> 1, hp = tid & 1;  // hp selects head parity
    const int head = head0 + hp;
    const int pos = (bm + row) & 1023;
    const u16* s = ct + row * CTS + hp * 64;
    u16* base = dst0 + ((size_t)(b * 12 + head)) * 65536;
    if (which == 0) {
      const int qsub = pos >> 5, lq = pos & 31;
#pragma unroll
      for (int g = 0; g < 8; ++g) {
        const int c = g >> 1, hi = g & 1;
        *(ushort8*)(base + ((qsub * 4 + c) * 64 + hi * 32 + lq) * 8) =
            *(const ushort8*)(s + g * 8);
      }
    } else {
      const int t = pos >> 6, hf = (pos >> 5) & 1, lq = pos & 31;
#pragma unroll
      for (int g = 0; g < 8; ++g) {
        const int c = g >> 1, hi = g & 1;
        *(ushort8*)(base + (((t * 4 + c) * 2 + hf) * 64 + hi * 32 + lq) * 8) =
            *(const ushort8*)(s + g * 8);
      }
    }
  } else {
    const int c = tid >> 1, seg = tid & 1;
    const int head = head0 + (c >> 6), dd = c & 63;
    const int posbase = (bm & 1023) + seg * 64;
    const int t = posbase >> 6;
    const int half = dd >> 5, lqd = dd & 31;
    u16* base = vto + ((size_t)(b * 12 + head)) * 65536;
    const u16* s = ct + (seg * 64) * CTS + c;
#pragma unroll
    for (int g = 0; g < 8; ++g) {
      ushort8 o;
#pragma unroll
      for (int e = 0; e < 8; ++e) o[e] = s[(g * 8 + e) * CTS];
      *(ushort8*)(base + (((t * 4 + (g >> 1)) * 2 + half) * 64 + (g & 1) * 32 + lqd) * 8) = o;
    }
  }
}

// ---------------- 64x64 bf16 GEMM for proj (T4 counted vmcnt too) ------------
__global__ __launch_bounds__(256) void gemm64(
    const u16* __restrict__ A, const u16* __restrict__ B,
    const float* __restrict__ bias, float* __restrict__ fout,
    int M, int N, int K) {
  __shared__ u16 smem[2 * 8192];  // [2 dbuf][A 4096 + B 4096 u16] = 32 KB
  const int tid = threadIdx.x;
  const int lane = tid & 63, wave = tid >> 6;
  const int wr = wave >> 1, wc = wave & 1;
  const int l15 = lane & 15, l4 = lane >> 4;
  const int fid = blockIdx.y * gridDim.x + blockIdx.x;
  const int cpx = (gridDim.x * gridDim.y) >> 3;  // 768 % 8 == 0
  const int swz = (fid & 7) * cpx + (fid >> 3);
  const int bxs = swz % gridDim.x, bys = swz / gridDim.x;
  const int bm = bys << 6, bn = bxs << 6;
  f32x4 acc[2][2] = {};
  const int nkt = K >> 6;

#define STAGE64(buf, kt)                                                      \
  {                                                                           \
    u16* As_ = smem + (buf) * 8192;                                           \
    u16* Bs_ = As_ + 4096;                                                    \
    const int k0_ = (kt) << 6;                                                \
    _Pragma("unroll") for (int j = 0; j < 2; ++j) {                           \
      const int cbase = j * 256 + wave * 64;                                  \
      const int chunk = cbase + lane;                                         \
      const int row = chunk >> 3;                                             \
      const int co = (((chunk & 7) ^ (row & 7)) << 3);                        \
      gload_lds16(A + (size_t)(bm + row) * K + k0_ + co, As_ + cbase * 8);    \
      gload_lds16(B + (size_t)(bn + row) * K + k0_ + co, Bs_ + cbase * 8);    \
    }                                                                         \
  }

  STAGE64(0, 0)
  int cur = 0;
  for (int kt = 0; kt < nkt; ++kt) {
    if (kt + 1 < nkt) {
      STAGE64(cur ^ 1, kt + 1)
      asm volatile("s_waitcnt vmcnt(4)" ::: "memory");
    } else {
      asm volatile("s_waitcnt vmcnt(0)" ::: "memory");
    }
    __builtin_amdgcn_s_barrier();  // B1
    const u16* As = smem + cur * 8192;
    const u16* Bs = As + 4096;
    short8 af[2][2], bf[2][2];
#pragma unroll
    for (int kc = 0; kc < 2; ++kc)
#pragma unroll
      for (int i = 0; i < 2; ++i) {
        const int rA = wr * 32 + i * 16 + l15;
        const int rB = wc * 32 + i * 16 + l15;
        af[kc][i] = *(const short8*)((const char*)As +
            (((rA * 64 + kc * 32 + l4 * 8) * 2) ^ ((rA & 7) << 4)));
        bf[kc][i] = *(const short8*)((const char*)Bs +
            (((rB * 64 + kc * 32 + l4 * 8) * 2) ^ ((rB & 7) << 4)));
      }
#pragma unroll
    for (int kc = 0; kc < 2; ++kc)
#pragma unroll
      for (int mi = 0; mi < 2; ++mi)
#pragma unroll
        for (int ni = 0; ni < 2; ++ni)
          acc[mi][ni] = __builtin_amdgcn_mfma_f32_16x16x32_bf16(
              af[kc][mi], bf[kc][ni], acc[mi][ni], 0, 0, 0);
    __builtin_amdgcn_s_barrier();  // B2
    cur ^= 1;
  }
#undef STAGE64

#pragma unroll
  for (int ni = 0; ni < 2; ++ni) {
    const int col = wc * 32 + ni * 16 + l15;
    const float bv = bias[bn + col];
#pragma unroll
    for (int mi = 0; mi < 2; ++mi)
#pragma unroll
      for (int j = 0; j < 4; ++j) {
        const int row = wr * 32 + mi * 16 + l4 * 4 + j;
        fout[(size_t)(bm + row) * N + bn + col] = acc[mi][ni][j] + bv;
      }
  }
}

// ---------------- fused attention; rel_h AND rel_w fused via LDS bounce -------
// grid (48 bh, 16 qtiles64), 256 threads = 4 waves = (2 q-subtiles x 2 key-halves).
// R19-exact structure (best known: 77.9 us). K register-prefetched one tile
// ahead; V issued same-iteration (R20's V-prefetch pushed VGPR 112->144,
// waves/SIMD 4->3, and REGRESSED — reverted). rel phase fused via the
// R17-acquitted LDS-bounce pattern; 'part' aliases the rel region.
__global__ __launch_bounds__(256) void attn_kernel(
    const u16* __restrict__ pq, const u16* __restrict__ pk,
    const u16* __restrict__ pv, const u16* __restrict__ th,
    const u16* __restrict__ tw, u16* __restrict__ aout) {
  const int bh = blockIdx.x, qt = blockIdx.y;
  const int tid = threadIdx.x, lane = tid & 63, wave = tid >> 6;
  const int wq = wave >> 1, wk = wave & 1;
  const int lq = lane & 31, hi = lane >> 5;
  const int q0 = qt * 64 + wq * 32;
  const u16* Qb = pq + (size_t)bh * 65536;
  const u16* Kb = pk + (size_t)bh * 65536;
  const u16* Vb = pv + (size_t)bh * 65536;
  __shared__ float lsums[2][2][32];
  __shared__ char shraw[24576];          // pd[2][64][32] + rh[2][32][32], then part
  float* pd = (float*)shraw;             // [wq][j][q]
  float* rhl = (float*)(shraw + 16384);  // [wq][kh][q]
  float* part = (float*)shraw;           // [wq][wk][lane][17] (aliases; see barriers)
  const int qsub = qt * 2 + wq;          // spatial h of this wave's q-rows
  short8 qf[4];
#pragma unroll
  for (int c = 0; c < 4; ++c)
    qf[c] = *(const short8*)(Qb + ((qsub * 4 + c) * 64 + lane) * 8);
  // issue first K tile early; rel computation below covers its latency
  short8 kf[2][8];
  {
    const int t0 = wk * 8;
#pragma unroll
    for (int c = 0; c < 4; ++c) {
      kf[0][c]     = *(const short8*)(Kb + (((t0 * 4 + c) * 2 + 0) * 64 + lane) * 8);
      kf[0][4 + c] = *(const short8*)(Kb + (((t0 * 4 + c) * 2 + 1) * 64 + lane) * 8);
    }
  }
  if (wk == 0) {
    // ---- rel_w: pd[j][q] = 8*dot(Tw[j], q) ----
    f32x16 pa{}, pb{};
    const int trB = (lq == 31) ? 62 : 32 + lq;  // clamp; pd[63] never consumed
#pragma unroll
    for (int c = 0; c < 4; ++c) {
      short8 ta = *(const short8*)(tw + (lq * 64 + c * 16 + hi * 8));
      short8 tb = *(const short8*)(tw + (trB * 64 + c * 16 + hi * 8));
      pa = __builtin_amdgcn_mfma_f32_32x32x16_bf16(ta, qf[c], pa, 0, 0, 0);
      pb = __builtin_amdgcn_mfma_f32_32x32x16_bf16(tb, qf[c], pb, 0, 0, 0);
    }
#pragma unroll
    for (int r = 0; r < 16; ++r) {
      const int j = (r & 3) + 8 * (r >> 2) + 4 * hi;
      pd[(wq * 64 + j) * 32 + lq] = pa[r] * 8.0f;
      pd[(wq * 64 + 32 + j) * 32 + lq] = pb[r] * 8.0f;
    }
  } else {
    // ---- rel_h (swapped orientation): rh[kh][q] = 8*dot(Th[qsub-kh+31], q) ----
    f32x16 rha{};
    const int trh = qsub - lq + 31;  // in [qsub, qsub+31] subset of [0,62]
#pragma unroll
    for (int c = 0; c < 4; ++c) {
      short8 ta = *(const short8*)(th + (trh * 64 + c * 16 + hi * 8));
      rha = __builtin_amdgcn_mfma_f32_32x32x16_bf16(ta, qf[c], rha, 0, 0, 0);
    }
#pragma unroll
    for (int r = 0; r < 16; ++r) {
      const int kh = (r & 3) + 8 * (r >> 2) + 4 * hi;
      rhl[(wq * 32 + kh) * 32 + lq] = rha[r] * 8.0f;
    }
  }
  __syncthreads();  // pd + rhl ready
  float rhv[16];
#pragma unroll
  for (int i = 0; i < 16; ++i)
    rhv[i] = rhl[(wq * 32 + 16 * wk + i) * 32 + lq];
  float rw[16];
#pragma unroll
  for (int r = 0; r < 16; ++r)
    rw[r] = pd[(wq * 64 + lq + 31 - ((r & 3) + 8 * (r >> 2) + 4 * hi)) * 32 + lq];
  __syncthreads();  // all pd/rhl reads done -> 'part' may alias the region
  f32x16 o0{}, o1{};
  float lsum = 0.f;
#pragma unroll
  for (int t = 0; t < 8; ++t) {
    const int tt = wk * 8 + t;
    const int cur = t & 1, nxt = cur ^ 1;
    // (1) V(t) FIRST: PV then waits only on loads <= V(t) (in-order vmcnt).
    short8 vb0[4], vb1[4];
#pragma unroll
    for (int cc = 0; cc < 4; ++cc) {
      vb0[cc] = *(const short8*)(Vb + (((tt * 4 + cc) * 2 + 0) * 64 + lane) * 8);
      vb1[cc] = *(const short8*)(Vb + (((tt * 4 + cc) * 2 + 1) * 64 + lane) * 8);
    }
    // (2) K(t+1) prefetch LAST: nothing this iteration waits on it.
    if (t < 7) {
      const int tn = tt + 1;
#pragma unroll
      for (int c = 0; c < 4; ++c) {
        kf[nxt][c]     = *(const short8*)(Kb + (((tn * 4 + c) * 2 + 0) * 64 + lane) * 8);
        kf[nxt][4 + c] = *(const short8*)(Kb + (((tn * 4 + c) * 2 + 1) * 64 + lane) * 8);
      }
    }
    // QK^T from zero C-init: K is in registers (prefetched) -> no wait
    f32x16 s0{}, s1{};
    __builtin_amdgcn_s_setprio(1);
#pragma unroll
    for (int c = 0; c < 4; ++c) {
      s0 = __builtin_amdgcn_mfma_f32_32x32x16_bf16(kf[cur][c], qf[c], s0, 0, 0, 0);
      s1 = __builtin_amdgcn_mfma_f32_32x32x16_bf16(kf[cur][4 + c], qf[c], s1, 0, 0, 0);
    }
    __builtin_amdgcn_s_setprio(0);
    // bias from REGISTERS (rhv static-indexed: t is fully unrolled)
    const float rh0 = rhv[2 * t], rh1 = rhv[2 * t + 1];
    // |S'| <= ~4.5 -> exp2 without max-subtract (log2e folded upstream)
#pragma unroll
    for (int r = 0; r < 16; ++r) {
      s0[r] = exp2f(s0[r] + (rh0 + rw[r]));
      s1[r] = exp2f(s1[r] + (rh1 + rw[r]));
    }
#pragma unroll
    for (int r = 0; r < 16; ++r) lsum += s0[r] + s1[r];
    // HW pack to bf16 + permlane half-exchange -> PV A-fragments (T12)
    unsigned int pw[16];
#pragma unroll
    for (int j = 0; j < 8; ++j) pw[j] = cvtpk(s0[2 * j], s0[2 * j + 1]);
#pragma unroll
    for (int j = 0; j < 8; ++j) pw[8 + j] = cvtpk(s1[2 * j], s1[2 * j + 1]);
    plswap(pw[0], pw[2]);  plswap(pw[1], pw[3]);
    plswap(pw[4], pw[6]);  plswap(pw[5], pw[7]);
    plswap(pw[8], pw[10]); plswap(pw[9], pw[11]);
    plswap(pw[12], pw[14]); plswap(pw[13], pw[15]);
    __builtin_amdgcn_s_setprio(1);
#pragma unroll
    for (int cc = 0; cc < 4; ++cc) {
      uint4v w4 = {pw[cc * 4 + 0], pw[cc * 4 + 1], pw[cc * 4 + 2], pw[cc * 4 + 3]};
      short8 pa = __builtin_bit_cast(short8, w4);
      o0 = __builtin_amdgcn_mfma_f32_32x32x16_bf16(pa, vb0[cc], o0, 0, 0, 0);
      o1 = __builtin_amdgcn_mfma_f32_32x32x16_bf16(pa, vb1[cc], o1, 0, 0, 0);
    }
    __builtin_amdgcn_s_setprio(0);
  }
  lsum += __shfl_xor(lsum, 32, 64);
  if (hi == 0) lsums[wq][wk][lq] = lsum;
  // store the O-half this wave will NOT finalize (wk==0 finalizes d<32 -> stores o1)
#pragma unroll
  for (int r = 0; r < 16; ++r)
    part[((wq * 2 + wk) * 64 + lane) * 17 + r] = wk ? o0[r] : o1[r];
  __syncthreads();
  const int b = bh / 12, head = bh - b * 12;
  u16* outp = aout + (size_t)b * 1024 * 768 + head * 64 + wk * 32;
#pragma unroll
  for (int r = 0; r < 16; ++r) {
    const int qr = (r & 3) + 8 * (r >> 2) + 4 * hi;
    const float inv = 1.0f / (lsums[wq][0][qr] + lsums[wq][1][qr]);
    const float own = wk ? o1[r] : o0[r];
    const float val = own + part[((wq * 2 + (wk ^ 1)) * 64 + lane) * 17 + r];
    outp[(size_t)(q0 + qr) * 768 + lq] = f2bf(val * inv);
  }
}

// ---------------- launch ----------------
extern "C" void kernel_launch(void* const* d_in, const int* in_sizes, int n_in,
                              void* d_out, int out_size, void* d_ws, size_t ws_size,
                              hipStream_t stream) {
  const float* x = (const float*)d_in[0];
  const float* qkv_w = (const float*)d_in[1];
  const float* qkv_b = (const float*)d_in[2];
  const float* proj_w = (const float*)d_in[3];
  const float* proj_b = (const float*)d_in[4];
  const float* rph = (const float*)d_in[5];
  const float* rpw = (const float*)d_in[6];
  float* out = (float*)d_out;
  char* ws = (char*)d_ws;
  u16* xb     = (u16*)(ws + 0);
  u16* wqkv   = (u16*)(ws + 6291456);
  u16* wproj  = (u16*)(ws + 9830400);
  u16* pq     = (u16*)(ws + 11010048);
  u16* pk     = (u16*)(ws + 17301504);
  u16* pv     = (u16*)(ws + 23592960);
  u16* aout   = (u16*)(ws + 42467328);
  u16* rphb   = (u16*)(ws + 48758784);
  u16* rpwb   = (u16*)(ws + 48766848);

  cvt_all<<<1024, 256, 0, stream>>>(x, xb, 3145728, qkv_w, wqkv, 1769472,
                                    proj_w, wproj, 589824, rph, rphb, 4032,
                                    rpw, rpwb, 4032);
  gemm128q<<<dim3(18, 32), 256, 0, stream>>>(xb, wqkv, qkv_b, pq, pk, pv,
                                             4096, 2304, 768);
  attn_kernel<<<dim3(48, 16), 256, 0, stream>>>(pq, pk, pv, rphb, rpwb, aout);
  gemm64<<<dim3(12, 64), 256, 0, stream>>>(aout, wproj, proj_b, out,
                                           4096, 768, 768);
}